// Round 1
// 1161.725 us; speedup vs baseline: 1.0193x; 1.0193x over previous
//
#include <hip/hip_runtime.h>
#include <hip/hip_bf16.h>
#include <math.h>

typedef unsigned short u16;
typedef unsigned int   u32;
typedef __attribute__((ext_vector_type(8))) short short8v;
typedef __attribute__((ext_vector_type(4))) float f32x4;

#define TILE 16

// ---------------------------------------------------------------------------
// ws layout (float offsets):
//  [0..357)    : the 9 real-basis w3j tensors (see OFF[] below)
//  [368]       : dtype flag (int; 1 = inputs are bf16, 0 = f32)
//  [369]       : mfma-layout probe OK flag (int)
//  [384..8576) : Wg1 f32   (8192)
//  [8576..)    : Wg2       (9216)
//  [17792..)   : WU0 (2048) [19840..): WU1 (1024) [20864..): WU2 (512)
//  [21376..)   : WV0 (2048) [23424..): WV1 (1024) [24448..): WV2 (512)
//  [24960..)   : bg1 (64)   [25024..): bg2 (144)  [25168..): C9 (9)
//  [25216..)   : res accumulator (G*9 f32)
//  float 44032 (= u16 88064): expanded bf16 weight tables (see WSH_*)
// ---------------------------------------------------------------------------
#define WS_FLAG  368
#define WS_MOK   369
#define WS_WG1   384
#define WS_WG2   8576
#define WS_WU0   17792
#define WS_WU1   19840
#define WS_WU2   20864
#define WS_WV0   21376
#define WS_WV1   23424
#define WS_WV2   24448
#define WS_BG1   24960
#define WS_BG2   25024
#define WS_C9    25168
#define WS_RES   25216

// u16-element offsets into ws for bf16 transposed/expanded weights
#define WSH_BG1T 88064    //  64 x 128   Bg1T[n][k] = Wg1[k][n]
#define WSH_BG2T 96256    // 144 x  64   Bg2T[n][k] = Wg2[k][n]
#define WSH_B0T  105472   //  32 x 128   [U16|V16][k]
#define WSH_B1T  109568   //  96 x 192   zero-expanded l=1 (cols (uv,i,v), k=3u+i)
#define WSH_B2T  128000   // 160 x 160   zero-expanded l=2 (cols (uv,i,v), k=5u+i)
#define WS_NEED_BYTES 307200

__device__ __forceinline__ float b2f(u16 u){
  return __uint_as_float(((u32)u) << 16);
}
__device__ __forceinline__ u16 f2b(float f){
  u32 x = __float_as_uint(f);
  return (u16)((x + 0x7fffu + ((x >> 16) & 1u)) >> 16);
}
__device__ __forceinline__ float ldconv(const void* p, int i, int isbf){
  return isbf ? b2f(((const u16*)p)[i]) : ((const float*)p)[i];
}

// ---------------------------------------------------------------------------
// dtype detection
// ---------------------------------------------------------------------------
__global__ void detect_kernel(const u32* __restrict__ words, int* __restrict__ flag){
  int t = threadIdx.x;
  int cnt = 0;
  for (int i = 0; i < 16; i++){
    u32 w = words[t*16 + i];
    u32 e = (w >> 7) & 0xFF;
    cnt += (e >= 117 && e <= 137) ? 1 : 0;
  }
  #pragma unroll
  for (int m = 1; m < 64; m <<= 1) cnt += __shfl_xor(cnt, m, 64);
  if (t == 0) *flag = (cnt > 512) ? 1 : 0;
}

// ---------------------------------------------------------------------------
// Wigner 3j setup
// ---------------------------------------------------------------------------
__device__ double factd(int n){ double r=1.0; for(int i=2;i<=n;++i) r*=(double)i; return r; }

__device__ double su2_cg(int j1,int m1,int j2,int m2,int j3,int m3){
  if (m1+m2 != m3) return 0.0;
  int vmin = max(max(-j1+j2+m3, -j1+m1), 0);
  int vmax = min(min(j2+j3+m1, j3-j1+j2), j3+m3);
  double C = sqrt((2.0*j3+1.0)
      * factd(j3+j1-j2)*factd(j3-j1+j2)*factd(j1+j2-j3)*factd(j3+m3)*factd(j3-m3)
      / (factd(j1+j2+j3+1)*factd(j1-m1)*factd(j1+m1)*factd(j2-m2)*factd(j2+m2)));
  double S = 0.0;
  for (int v=vmin; v<=vmax; ++v){
    double t = factd(j2+j3+m1-v)*factd(j1-m1+v)
             / (factd(v)*factd(j3-j1+j2-v)*factd(j3+m3-v)*factd(v+j1-j2-m3));
    S += ((v+j2+m2)&1) ? -t : t;
  }
  return C*S;
}

__device__ void qmat_lds(int l, double* qre, double* qim){
  int d = 2*l+1;
  for (int i=0;i<d*d;i++){ qre[i]=0.0; qim[i]=0.0; }
  double s = 1.0/sqrt(2.0);
  for (int m=-l; m<0; ++m){
    qre[(l+m)*d + (l-m)] = s;
    qim[(l+m)*d + (l+m)] = -s;
  }
  qre[l*d + l] = 1.0;
  for (int m=1; m<=l; ++m){
    double sgn = (m&1) ? -1.0 : 1.0;
    qre[(l+m)*d + (l+m)] = sgn*s;
    qim[(l+m)*d + (l-m)] = sgn*s;
  }
  double fr, fi;
  switch (l & 3){ case 0: fr=1; fi=0; break; case 1: fr=0; fi=-1; break;
                  case 2: fr=-1; fi=0; break; default: fr=0; fi=1; }
  for (int i=0;i<d*d;i++){
    double a=qre[i], b=qim[i];
    qre[i]=a*fr-b*fi; qim[i]=a*fi+b*fr;
  }
}

__global__ void setup_kernel(float* __restrict__ ws){
  __shared__ double q1r[25], q1i[25], q2r[25], q2i[25], q3r[25], q3i[25];
  __shared__ double red[128];
  const int L1[9]={0,0,1,1,1,2,2,2,2};
  const int L2[9]={0,2,1,1,1,0,2,2,2};
  const int L3[9]={0,2,0,1,2,2,0,1,2};
  const int OFF[9]={0,1,26,35,62,107,132,157,232};
  const int b = blockIdx.x;
  const int l1=L1[b], l2=L2[b], l3=L3[b];
  const int d1=2*l1+1, d2=2*l2+1, d3=2*l3+1;
  const int tot = d1*d2*d3;
  const int t = threadIdx.x;

  if (t==0) qmat_lds(l1, q1r, q1i);
  if (t==1) qmat_lds(l2, q2r, q2i);
  if (t==2) qmat_lds(l3, q3r, q3i);
  __syncthreads();

  double ar = 0.0;
  if (t < tot){
    const int j = t/(d2*d3), rem = t - j*(d2*d3), l = rem/d3, m = rem - l*d3;
    for (int i=0;i<d1;i++){
      double a1r=q1r[i*d1+j], a1i=q1i[i*d1+j];
      for (int k=0;k<d2;k++){
        double a2r=q2r[k*d2+l], a2i=q2i[k*d2+l];
        double t12r = a1r*a2r - a1i*a2i;
        double t12i = a1r*a2i + a1i*a2r;
        for (int n=0;n<d3;n++){
          double c = su2_cg(l1, i-l1, l2, k-l2, l3, n-l3);
          if (c==0.0) continue;
          double a3r = q3r[n*d3+m], a3i = -q3i[n*d3+m]; // conj
          ar += c*(t12r*a3r - t12i*a3i);
        }
      }
    }
  }
  red[t] = ar*ar;
  __syncthreads();
  for (int s=64; s>0; s>>=1){
    if (t < s) red[t] += red[t+s];
    __syncthreads();
  }
  double nrm = sqrt(red[0]);
  if (t < tot) ws[OFF[b] + t] = (float)(ar/nrm);
}

// ---------------------------------------------------------------------------
// Weight canonicalization + bf16 transposed/expanded tables for the MFMA path
// ---------------------------------------------------------------------------
__global__ void convert_weights(
    const void* Wg1, const void* Wg2,
    const void* WU0, const void* WU1, const void* WU2,
    const void* WV0, const void* WV1, const void* WV2,
    const void* bg1, const void* bg2,
    const void* Wp0, const void* Wp1, const void* Wp2,
    float* __restrict__ ws)
{
  const int isbf = ((const int*)ws)[WS_FLAG];
  const int b = blockIdx.x, t = threadIdx.x;
  u16* wh = (u16*)ws;
  if (b < 10){
    const void* src[10] = {Wg1,Wg2,WU0,WU1,WU2,WV0,WV1,WV2,bg1,bg2};
    const int   sz[10]  = {8192,9216,2048,1024,512,2048,1024,512,64,144};
    const int   off[10] = {WS_WG1,WS_WG2,WS_WU0,WS_WU1,WS_WU2,WS_WV0,WS_WV1,WS_WV2,WS_BG1,WS_BG2};
    const void* s = src[b]; float* d = ws + off[b]; int n = sz[b];
    for (int i = t; i < n; i += 256) d[i] = ldconv(s, i, isbf);
  } else if (b == 10){
    if (t == 0){
      float* C9 = ws + WS_C9;
      const int l3k[9]  = {0,2,0,1,2,2,0,1,2};
      const int idxk[9] = {0,0,1,0,1,2,2,1,3};
      for (int k=0;k<9;k++){
        int l3 = l3k[k];
        const void* wp = (l3==0) ? Wp0 : (l3==1) ? Wp1 : Wp2;
        float wpv = ldconv(wp, idxk[k], isbf);
        float len = (l3==0) ? 3.f : (l3==1) ? 2.f : 4.f;
        C9[k] = sqrtf((2.f*l3 + 1.f)/16.f) * wpv * rsqrtf(len);
      }
    }
  } else if (b == 11){          // Bg1T[n=64][k=128] = Wg1[k][n]
    for (int i=t;i<8192;i+=256){
      int n = i >> 7, k = i & 127;
      wh[WSH_BG1T + i] = f2b(ldconv(Wg1, k*64 + n, isbf));
    }
  } else if (b == 12){          // Bg2T[n=144][k=64] = Wg2[k][n]
    for (int i=t;i<9216;i+=256){
      int n = i >> 6, k = i & 63;
      wh[WSH_BG2T + i] = f2b(ldconv(Wg2, k*144 + n, isbf));
    }
  } else if (b == 13){          // B0T[n=32][k=128] = [WU0|WV0]^T
    for (int i=t;i<4096;i+=256){
      int n = i >> 7, k = i & 127;
      float v = (n < 16) ? ldconv(WU0, k*16 + n, isbf)
                         : ldconv(WV0, k*16 + (n-16), isbf);
      wh[WSH_B0T + i] = f2b(v);
    }
  } else if (b == 14){          // B1T[n=96][k=192], n=(uv*48 + i*16 + v), k=3u+i
    for (int i=t;i<18432;i+=256){
      int n = i / 192, k = i - n*192;
      int uv = n / 48, rem = n - uv*48, ii = rem >> 4, vv = rem & 15;
      float val = 0.f;
      if (k % 3 == ii){
        int u = k / 3;
        val = ldconv(uv ? WV1 : WU1, u*16 + vv, isbf);
      }
      wh[WSH_B1T + i] = f2b(val);
    }
  } else if (b == 15){          // B2T[n=160][k=160], n=(uv*80 + i*16 + v), k=5u+i
    for (int i=t;i<25600;i+=256){
      int n = i / 160, k = i - n*160;
      int uv = n / 80, rem = n - uv*80, ii = rem >> 4, vv = rem & 15;
      float val = 0.f;
      if (k % 5 == ii){
        int u = k / 5;
        val = ldconv(uv ? WV2 : WU2, u*16 + vv, isbf);
      }
      wh[WSH_B2T + i] = f2b(val);
    }
  }
}

// ---------------------------------------------------------------------------
// MFMA lane-layout probe: verifies (A,B,D) mappings with asymmetric integer
// patterns (transpose-detecting). Sets ws[WS_MOK]=1 only on exact match.
// ---------------------------------------------------------------------------
__global__ void probe_kernel(float* __restrict__ ws){
  __shared__ u16 A[512];   // [16][32] row-major
  __shared__ u16 B[512];   // [32][16] row-major
  int t = threadIdx.x;
  for (int i=t;i<512;i+=64){
    int m = i >> 5, k = i & 31;
    A[i] = f2b((float)(((3*m + k) % 7) - 3));
    int kk = i >> 4, n = i & 15;
    B[i] = f2b((float)(((2*kk + 5*n) % 9) - 4));
  }
  __syncthreads();
  int v = t & 15, g4 = t >> 4;
  short8v a, b;
  #pragma unroll
  for (int j=0;j<8;j++){
    a[j] = (short)A[v*32 + 8*g4 + j];
    b[j] = (short)B[(8*g4 + j)*16 + v];
  }
  f32x4 c = {0.f,0.f,0.f,0.f};
  c = __builtin_amdgcn_mfma_f32_16x16x32_bf16(a, b, c, 0, 0, 0);
  int ok = 1;
  #pragma unroll
  for (int r=0;r<4;r++){
    int row = 4*g4 + r;
    float ref = 0.f;
    for (int k=0;k<32;k++) ref += b2f(A[row*32+k]) * b2f(B[k*16+v]);
    if (fabsf(c[r] - ref) > 0.25f) ok = 0;
  }
  #pragma unroll
  for (int m=1;m<64;m<<=1) ok &= __shfl_xor(ok, m, 64);
  if (t == 0) ((int*)ws)[WS_MOK] = ok;
}

// ---------------------------------------------------------------------------
// MFMA main kernel (bf16 inputs only). One wave = 16 atoms; 4 waves/block.
// All GEMMs via mfma_f32_16x16x32_bf16 with direct-from-global fragments.
// ---------------------------------------------------------------------------
__global__ __launch_bounds__(256,3) void mfma_kernel(
    const int* __restrict__ batch,
    const void* __restrict__ xscv,
    const void* __restrict__ xspv,
    const float* __restrict__ ws,
    float* __restrict__ res,
    int N)
{
  const int isbf = ((const int*)ws)[WS_FLAG];
  const int mok  = ((const int*)ws)[WS_MOK];
  if (!(isbf && mok)) return;

  __shared__ __align__(16) u16 H1hi[4][16][72];
  __shared__ __align__(16) u16 H1lo[4][16][72];

  const int tid = threadIdx.x;
  const int wave = tid >> 6, lane = tid & 63;
  const int v = lane & 15, g4 = lane >> 4;
  const int tile = blockIdx.x*4 + wave;
  const int n0 = tile * TILE;
  if (n0 >= N) return;

  const u16* xsc = (const u16*)xscv;
  const u16* xsp = (const u16*)xspv;
  const u16* wb  = (const u16*)ws;

  int rowA = n0 + v; if (rowA >= N) rowA = N - 1;

  // ---- G1: H1pre = Xsc(16x128) @ Wg1(128x64) --------------------------------
  f32x4 accg[4];
  #pragma unroll
  for (int nt=0;nt<4;nt++) accg[nt] = (f32x4){0.f,0.f,0.f,0.f};
  {
    const u16* aP = xsc + (size_t)rowA*128 + 8*g4;
    const u16* bP = wb + WSH_BG1T + v*128 + 8*g4;
    #pragma unroll
    for (int kt=0;kt<4;kt++){
      short8v a = *(const short8v*)(aP + kt*32);
      #pragma unroll
      for (int nt=0;nt<4;nt++){
        short8v b = *(const short8v*)(bP + nt*2048 + kt*32);
        accg[nt] = __builtin_amdgcn_mfma_f32_16x16x32_bf16(a, b, accg[nt], 0, 0, 0);
      }
    }
  }
  // bias + silu + hi/lo bf16 split -> LDS transpose (D: row=atom, col=feat)
  #pragma unroll
  for (int nt=0;nt<4;nt++){
    float bb = ws[WS_BG1 + nt*16 + v];
    #pragma unroll
    for (int r=0;r<4;r++){
      float hs = accg[nt][r] + bb;
      float h  = hs / (1.f + __expf(-hs));
      u16 hi = f2b(h);
      float lo = h - b2f(hi);
      int atom = 4*g4 + r;
      H1hi[wave][atom][nt*16 + v] = hi;
      H1lo[wave][atom][nt*16 + v] = f2b(lo);
    }
  }
  // same-wave ds_write -> ds_read: compiler orders via lgkmcnt (aliasing dep)

  // ---- G2: W = H1(16x64) @ Wg2(64x144), split-bf16 for f32-grade precision --
  f32x4 accw[9];
  #pragma unroll
  for (int nt=0;nt<9;nt++) accw[nt] = (f32x4){0.f,0.f,0.f,0.f};
  {
    const u16* hH = &H1hi[wave][v][8*g4];
    const u16* hL = &H1lo[wave][v][8*g4];
    const u16* bP = wb + WSH_BG2T + v*64 + 8*g4;
    #pragma unroll
    for (int kt=0;kt<2;kt++){
      short8v ah = *(const short8v*)(hH + kt*32);
      short8v al = *(const short8v*)(hL + kt*32);
      #pragma unroll
      for (int nt=0;nt<9;nt++){
        short8v b = *(const short8v*)(bP + nt*1024 + kt*32);
        accw[nt] = __builtin_amdgcn_mfma_f32_16x16x32_bf16(ah, b, accw[nt], 0, 0, 0);
        accw[nt] = __builtin_amdgcn_mfma_f32_16x16x32_bf16(al, b, accw[nt], 0, 0, 0);
      }
    }
  }
  float wkv[9][4];
  #pragma unroll
  for (int nt=0;nt<9;nt++){
    float bb = ws[WS_BG2 + nt*16 + v];
    float c9 = ws[WS_C9 + nt];               // uniform -> s_load
    #pragma unroll
    for (int r=0;r<4;r++) wkv[nt][r] = (accw[nt][r] + bb) * c9;
  }

  // ---- spherical linears ----------------------------------------------------
  const u16* spA = xsp + (size_t)rowA*480 + 8*g4;

  f32x4 acc0[2];
  #pragma unroll
  for (int nt=0;nt<2;nt++) acc0[nt] = (f32x4){0.f,0.f,0.f,0.f};
  {
    const u16* bP = wb + WSH_B0T + v*128 + 8*g4;
    #pragma unroll
    for (int kt=0;kt<4;kt++){
      short8v a = *(const short8v*)(spA + kt*32);
      #pragma unroll
      for (int nt=0;nt<2;nt++){
        short8v b = *(const short8v*)(bP + nt*2048 + kt*32);
        acc0[nt] = __builtin_amdgcn_mfma_f32_16x16x32_bf16(a, b, acc0[nt], 0, 0, 0);
      }
    }
  }
  f32x4 accA[6];
  #pragma unroll
  for (int nt=0;nt<6;nt++) accA[nt] = (f32x4){0.f,0.f,0.f,0.f};
  {
    const u16* bP = wb + WSH_B1T + v*192 + 8*g4;
    #pragma unroll
    for (int kt=0;kt<6;kt++){
      short8v a = *(const short8v*)(spA + 128 + kt*32);
      #pragma unroll
      for (int nt=0;nt<6;nt++){
        short8v b = *(const short8v*)(bP + nt*3072 + kt*32);
        accA[nt] = __builtin_amdgcn_mfma_f32_16x16x32_bf16(a, b, accA[nt], 0, 0, 0);
      }
    }
  }
  f32x4 accB[10];
  #pragma unroll
  for (int nt=0;nt<10;nt++) accB[nt] = (f32x4){0.f,0.f,0.f,0.f};
  {
    const u16* bP = wb + WSH_B2T + v*160 + 8*g4;
    #pragma unroll
    for (int kt=0;kt<5;kt++){
      short8v a = *(const short8v*)(spA + 320 + kt*32);
      #pragma unroll
      for (int nt=0;nt<10;nt++){
        short8v b = *(const short8v*)(bP + nt*2560 + kt*32);
        accB[nt] = __builtin_amdgcn_mfma_f32_16x16x32_bf16(a, b, accB[nt], 0, 0, 0);
      }
    }
  }

  // ---- phase 4: tensor products, u-reduction, merged segment atomics --------
  int bidr[4];
  #pragma unroll
  for (int r=0;r<4;r++){
    int n = n0 + 4*g4 + r;
    bidr[r] = (n < N) ? batch[n] : -1;
  }

  const float r128 = 0.088388347648318447f;
  const float r64  = 0.125f;
  const float r32  = 0.17677669529663689f;
  const float* J = ws;
  float pend[9];
  int pg = -1;

  #pragma unroll
  for (int r=0;r<4;r++){
    float hu0 = acc0[0][r]*r128, hv0 = acc0[1][r]*r128;
    float hu1[3], hv1[3], hu2[5], hv2[5];
    #pragma unroll
    for (int i=0;i<3;i++){ hu1[i] = accA[i][r]*r64; hv1[i] = accA[3+i][r]*r64; }
    #pragma unroll
    for (int i=0;i<5;i++){ hu2[i] = accB[i][r]*r32; hv2[i] = accB[5+i][r]*r32; }

    float t9[9] = {0,0,0,0,0,0,0,0,0};
    t9[0] += wkv[0][r]*J[0]*hu0*hv0;
    {
      float cw = wkv[1][r]*hu0;
      #pragma unroll
      for (int m=0;m<5;m++){
        float s=0.f;
        #pragma unroll
        for (int j=0;j<5;j++) s += J[1 + j*5 + m]*hv2[j];
        t9[4+m] += cw*s;
      }
    }
    {
      float s=0.f;
      #pragma unroll
      for (int i=0;i<3;i++)
        #pragma unroll
        for (int j=0;j<3;j++) s += J[26 + i*3 + j]*hu1[i]*hv1[j];
      t9[0] += wkv[2][r]*s;
    }
    {
      float sm[3]={0,0,0};
      #pragma unroll
      for (int i=0;i<3;i++)
        #pragma unroll
        for (int j=0;j<3;j++){
          float p = hu1[i]*hv1[j];
          #pragma unroll
          for (int m=0;m<3;m++) sm[m] += J[35 + (i*3+j)*3 + m]*p;
        }
      #pragma unroll
      for (int m=0;m<3;m++) t9[1+m] += wkv[3][r]*sm[m];
    }
    {
      float sm[5]={0,0,0,0,0};
      #pragma unroll
      for (int i=0;i<3;i++)
        #pragma unroll
        for (int j=0;j<3;j++){
          float p = hu1[i]*hv1[j];
          #pragma unroll
          for (int m=0;m<5;m++) sm[m] += J[62 + (i*3+j)*5 + m]*p;
        }
      #pragma unroll
      for (int m=0;m<5;m++) t9[4+m] += wkv[4][r]*sm[m];
    }
    {
      float cw = wkv[5][r]*hv0;
      #pragma unroll
      for (int m=0;m<5;m++){
        float s=0.f;
        #pragma unroll
        for (int i=0;i<5;i++) s += J[107 + i*5 + m]*hu2[i];
        t9[4+m] += cw*s;
      }
    }
    {
      float s=0.f;
      #pragma unroll
      for (int i=0;i<5;i++)
        #pragma unroll
        for (int j=0;j<5;j++) s += J[132 + i*5 + j]*hu2[i]*hv2[j];
      t9[0] += wkv[6][r]*s;
    }
    {
      float sm[3]={0,0,0};
      #pragma unroll
      for (int i=0;i<5;i++)
        #pragma unroll
        for (int j=0;j<5;j++){
          float p = hu2[i]*hv2[j];
          #pragma unroll
          for (int m=0;m<3;m++) sm[m] += J[157 + (i*5+j)*3 + m]*p;
        }
      #pragma unroll
      for (int m=0;m<3;m++) t9[1+m] += wkv[7][r]*sm[m];
    }
    {
      float sm[5]={0,0,0,0,0};
      #pragma unroll
      for (int i=0;i<5;i++)
        #pragma unroll
        for (int j=0;j<5;j++){
          float p = hu2[i]*hv2[j];
          #pragma unroll
          for (int m=0;m<5;m++) sm[m] += J[232 + (i*5+j)*5 + m]*p;
        }
      #pragma unroll
      for (int m=0;m<5;m++) t9[4+m] += wkv[8][r]*sm[m];
    }

    #pragma unroll
    for (int mask=1; mask<16; mask<<=1){
      #pragma unroll
      for (int s=0;s<9;s++) t9[s] += __shfl_xor(t9[s], mask, 64);
    }
    if (v == 0){
      int n = n0 + 4*g4 + r;
      if (n < N){
        int g = bidr[r];
        if (g == pg){
          #pragma unroll
          for (int s=0;s<9;s++) pend[s] += t9[s];
        } else {
          if (pg >= 0){
            float* rp = res + (size_t)pg*9;
            #pragma unroll
            for (int s=0;s<9;s++) atomicAdd(&rp[s], pend[s]);
          }
          pg = g;
          #pragma unroll
          for (int s=0;s<9;s++) pend[s] = t9[s];
        }
      }
    }
  }
  if (v == 0 && pg >= 0){
    float* rp = res + (size_t)pg*9;
    #pragma unroll
    for (int s=0;s<9;s++) atomicAdd(&rp[s], pend[s]);
  }
}

// ---------------------------------------------------------------------------
// Fallback scalar kernel (f32 inputs, or MFMA probe failure). Unchanged except
// the early-exit guard.
// ---------------------------------------------------------------------------
__device__ __forceinline__ void load8_bf16(const u16* p, float* dst){
  uint4 vv = *reinterpret_cast<const uint4*>(p);
  u32 w[4] = {vv.x, vv.y, vv.z, vv.w};
  #pragma unroll
  for (int q=0;q<4;q++){
    dst[2*q]   = __uint_as_float((w[q] & 0xffffu) << 16);
    dst[2*q+1] = __uint_as_float(w[q] & 0xffff0000u);
  }
}
__device__ __forceinline__ void load8_f32(const float* p, float* dst){
  float4 v0 = *reinterpret_cast<const float4*>(p);
  float4 v1 = *reinterpret_cast<const float4*>(p+4);
  dst[0]=v0.x; dst[1]=v0.y; dst[2]=v0.z; dst[3]=v0.w;
  dst[4]=v1.x; dst[5]=v1.y; dst[6]=v1.z; dst[7]=v1.w;
}

__global__ __launch_bounds__(256) void main_kernel(
    const int* __restrict__ batch,
    const void* __restrict__ xscv,
    const void* __restrict__ xspv,
    const float* __restrict__ ws,
    float* __restrict__ res,
    int N)
{
  {
    const int fb = ((const int*)ws)[WS_FLAG];
    const int mk = ((const int*)ws)[WS_MOK];
    if (fb && mk) return;   // MFMA path handled it
  }
  __shared__ float s_xsph[TILE][481];
  __shared__ float s_w[TILE][144];
  __shared__ float s_uni[4624];
  __shared__ float s_w3j[357];
  __shared__ float s_bg1[64];
  __shared__ float s_bg2[144];
  __shared__ float s_C[9];
  __shared__ int   s_batch[TILE];

  float (*s_xs)[128] = reinterpret_cast<float(*)[128]>(s_uni);
  float (*s_h1)[64]  = reinterpret_cast<float(*)[64]>(s_uni + 2048);
  float (*s_hU)[144] = reinterpret_cast<float(*)[144]>(s_uni);
  float (*s_hV)[144] = reinterpret_cast<float(*)[144]>(s_uni + 2304);

  const int tid  = threadIdx.x;
  const int wave = tid >> 6;
  const int lane = tid & 63;
  const int n0   = blockIdx.x * TILE;
  const int isbf = ((const int*)ws)[WS_FLAG];

  const float* wsWg1 = ws + WS_WG1;
  const float* wsWg2 = ws + WS_WG2;
  const float* wsWU0 = ws + WS_WU0;
  const float* wsWU1 = ws + WS_WU1;
  const float* wsWU2 = ws + WS_WU2;
  const float* wsWV0 = ws + WS_WV0;
  const float* wsWV1 = ws + WS_WV1;
  const float* wsWV2 = ws + WS_WV2;

  if (tid < TILE){ int n = n0 + tid; s_batch[tid] = (n < N) ? batch[n] : -1; }
  if (tid < 64)  s_bg1[tid] = ws[WS_BG1 + tid];
  if (tid < 144) s_bg2[tid] = ws[WS_BG2 + tid];
  if (tid < 9)   s_C[tid]   = ws[WS_C9 + tid];
  for (int i = tid; i < 357; i += 256) s_w3j[i] = ws[i];
  {
    int base = tid*8, row = base >> 7, col = base & 127;
    int n = n0 + row;
    if (n < N){
      if (isbf) load8_bf16((const u16*)xscv + (size_t)n*128 + col, &s_xs[row][col]);
      else      load8_f32 ((const float*)xscv + (size_t)n*128 + col, &s_xs[row][col]);
    } else { for (int q=0;q<8;q++) s_xs[row][col+q] = 0.f; }
  }
  {
    for (int it = tid; it < 960; it += 256){
      int base = it*8, row = base/480, col = base - row*480;
      int n = n0 + row;
      if (n < N){
        if (isbf) load8_bf16((const u16*)xspv + (size_t)n*480 + col, &s_xsph[row][col]);
        else      load8_f32 ((const float*)xspv + (size_t)n*480 + col, &s_xsph[row][col]);
      } else { for (int q=0;q<8;q++) s_xsph[row][col+q] = 0.f; }
    }
  }
  __syncthreads();

  {
    const int a0 = wave*4;
    float acc0=s_bg1[lane], acc1=acc0, acc2=acc0, acc3=acc0;
    for (int c=0;c<128;c++){
      float wv = wsWg1[c*64 + lane];
      acc0 += s_xs[a0+0][c]*wv;
      acc1 += s_xs[a0+1][c]*wv;
      acc2 += s_xs[a0+2][c]*wv;
      acc3 += s_xs[a0+3][c]*wv;
    }
    s_h1[a0+0][lane] = acc0/(1.f+__expf(-acc0));
    s_h1[a0+1][lane] = acc1/(1.f+__expf(-acc1));
    s_h1[a0+2][lane] = acc2/(1.f+__expf(-acc2));
    s_h1[a0+3][lane] = acc3/(1.f+__expf(-acc3));
  }
  __syncthreads();

  {
    const int a0 = wave*4;
    float acc[4][3];
    #pragma unroll
    for (int t=0;t<4;t++){
      acc[t][0] = s_bg2[lane];
      acc[t][1] = s_bg2[64+lane];
      acc[t][2] = (lane<16) ? s_bg2[128+lane] : 0.f;
    }
    for (int c=0;c<64;c++){
      float w0 = wsWg2[c*144 + lane];
      float w1 = wsWg2[c*144 + 64 + lane];
      float w2 = (lane<16) ? wsWg2[c*144 + 128 + lane] : 0.f;
      #pragma unroll
      for (int t=0;t<4;t++){
        float h = s_h1[a0+t][c];
        acc[t][0] += h*w0; acc[t][1] += h*w1; acc[t][2] += h*w2;
      }
    }
    #pragma unroll
    for (int t=0;t<4;t++){
      s_w[a0+t][lane]    = acc[t][0];
      s_w[a0+t][64+lane] = acc[t][1];
      if (lane < 16) s_w[a0+t][128+lane] = acc[t][2];
    }
  }
  __syncthreads();

  {
    const int a = tid >> 4, v = tid & 15;
    const float r128 = 0.088388347648318447f;
    const float r64  = 0.125f;
    const float r32  = 0.17677669529663689f;
    {
      float aU=0.f, aV=0.f;
      for (int u=0;u<128;u++){
        float x = s_xsph[a][u];
        aU += x*wsWU0[u*16+v];
        aV += x*wsWV0[u*16+v];
      }
      s_hU[a][v] = aU*r128; s_hV[a][v] = aV*r128;
    }
    {
      float aU[3]={0,0,0}, aV[3]={0,0,0};
      for (int u=0;u<64;u++){
        float wu = wsWU1[u*16+v], wv = wsWV1[u*16+v];
        #pragma unroll
        for (int i=0;i<3;i++){
          float x = s_xsph[a][128 + u*3 + i];
          aU[i] += x*wu; aV[i] += x*wv;
        }
      }
      #pragma unroll
      for (int i=0;i<3;i++){ s_hU[a][16+v*3+i]=aU[i]*r64; s_hV[a][16+v*3+i]=aV[i]*r64; }
    }
    {
      float aU[5]={0,0,0,0,0}, aV[5]={0,0,0,0,0};
      for (int u=0;u<32;u++){
        float wu = wsWU2[u*16+v], wv = wsWV2[u*16+v];
        #pragma unroll
        for (int i=0;i<5;i++){
          float x = s_xsph[a][320 + u*5 + i];
          aU[i] += x*wu; aV[i] += x*wv;
        }
      }
      #pragma unroll
      for (int i=0;i<5;i++){ s_hU[a][64+v*5+i]=aU[i]*r32; s_hV[a][64+v*5+i]=aV[i]*r32; }
    }
  }
  __syncthreads();

  {
    const int a = tid >> 4, u = tid & 15;
    float hu0 = s_hU[a][u], hv0 = s_hV[a][u];
    float hu1[3], hv1[3], hu2[5], hv2[5];
    #pragma unroll
    for (int i=0;i<3;i++){ hu1[i]=s_hU[a][16+u*3+i]; hv1[i]=s_hV[a][16+u*3+i]; }
    #pragma unroll
    for (int i=0;i<5;i++){ hu2[i]=s_hU[a][64+u*5+i]; hv2[i]=s_hV[a][64+u*5+i]; }
    float wk[9];
    #pragma unroll
    for (int k=0;k<9;k++) wk[k] = s_w[a][k*16+u];

    const float* J = s_w3j;
    float t9[9] = {0,0,0,0,0,0,0,0,0};

    t9[0] += s_C[0]*wk[0]*J[0]*hu0*hv0;
    {
      float cw = s_C[1]*wk[1]*hu0;
      #pragma unroll
      for (int m=0;m<5;m++){
        float s=0.f;
        #pragma unroll
        for (int j=0;j<5;j++) s += J[1 + j*5 + m]*hv2[j];
        t9[4+m] += cw*s;
      }
    }
    {
      float s=0.f;
      #pragma unroll
      for (int i=0;i<3;i++)
        #pragma unroll
        for (int j=0;j<3;j++) s += J[26 + i*3 + j]*hu1[i]*hv1[j];
      t9[0] += s_C[2]*wk[2]*s;
    }
    {
      float sm[3]={0,0,0};
      #pragma unroll
      for (int i=0;i<3;i++)
        #pragma unroll
        for (int j=0;j<3;j++){
          float p = hu1[i]*hv1[j];
          #pragma unroll
          for (int m=0;m<3;m++) sm[m] += J[35 + (i*3+j)*3 + m]*p;
        }
      float c = s_C[3]*wk[3];
      #pragma unroll
      for (int m=0;m<3;m++) t9[1+m] += c*sm[m];
    }
    {
      float sm[5]={0,0,0,0,0};
      #pragma unroll
      for (int i=0;i<3;i++)
        #pragma unroll
        for (int j=0;j<3;j++){
          float p = hu1[i]*hv1[j];
          #pragma unroll
          for (int m=0;m<5;m++) sm[m] += J[62 + (i*3+j)*5 + m]*p;
        }
      float c = s_C[4]*wk[4];
      #pragma unroll
      for (int m=0;m<5;m++) t9[4+m] += c*sm[m];
    }
    {
      float cw = s_C[5]*wk[5]*hv0;
      #pragma unroll
      for (int m=0;m<5;m++){
        float s=0.f;
        #pragma unroll
        for (int i=0;i<5;i++) s += J[107 + i*5 + m]*hu2[i];
        t9[4+m] += cw*s;
      }
    }
    {
      float s=0.f;
      #pragma unroll
      for (int i=0;i<5;i++)
        #pragma unroll
        for (int j=0;j<5;j++) s += J[132 + i*5 + j]*hu2[i]*hv2[j];
      t9[0] += s_C[6]*wk[6]*s;
    }
    {
      float sm[3]={0,0,0};
      #pragma unroll
      for (int i=0;i<5;i++)
        #pragma unroll
        for (int j=0;j<5;j++){
          float p = hu2[i]*hv2[j];
          #pragma unroll
          for (int m=0;m<3;m++) sm[m] += J[157 + (i*5+j)*3 + m]*p;
        }
      float c = s_C[7]*wk[7];
      #pragma unroll
      for (int m=0;m<3;m++) t9[1+m] += c*sm[m];
    }
    {
      float sm[5]={0,0,0,0,0};
      #pragma unroll
      for (int i=0;i<5;i++)
        #pragma unroll
        for (int j=0;j<5;j++){
          float p = hu2[i]*hv2[j];
          #pragma unroll
          for (int m=0;m<5;m++) sm[m] += J[232 + (i*5+j)*5 + m]*p;
        }
      float c = s_C[8]*wk[8];
      #pragma unroll
      for (int m=0;m<5;m++) t9[4+m] += c*sm[m];
    }

    #pragma unroll
    for (int mask=1; mask<16; mask<<=1){
      #pragma unroll
      for (int s=0;s<9;s++) t9[s] += __shfl_xor(t9[s], mask, 64);
    }
    if (u == 0 && (n0 + a) < N){
      int g = s_batch[a];
      float* r = res + (size_t)g*9;
      #pragma unroll
      for (int s=0;s<9;s++) atomicAdd(&r[s], t9[s]);
    }
  }
}

// ---------------------------------------------------------------------------
// Finish: res_sph (G x 9) -> out (G x 3 x 3) via Q_COB + CART permutation
// ---------------------------------------------------------------------------
__global__ void finish_kernel(const float* __restrict__ res,
                              const float* __restrict__ ws,
                              void* __restrict__ out, int G)
{
  int idx = blockIdx.x*256 + threadIdx.x;
  if (idx >= G*9) return;
  const int isbf = ((const int*)ws)[WS_FLAG];
  int g = idx/9, s = idx - g*9;
  int a = s/3, b = s - a*3;
  const int cart[3] = {2,0,1};
  int ca = cart[a], cb = cart[b];
  const float s3 = 1.7320508075688772f, s5 = 2.2360679774997896f;
  const float* r = res + (size_t)g*9;
  float acc = r[0]*ws[26 + ca*3 + cb];
  #pragma unroll
  for (int m=0;m<3;m++) acc += r[1+m]*s3*ws[35 + (ca*3+cb)*3 + m];
  #pragma unroll
  for (int m=0;m<5;m++) acc += r[4+m]*s5*ws[62 + (ca*3+cb)*5 + m];
  if (isbf) ((__hip_bfloat16*)out)[idx] = __float2bfloat16(acc);
  else      ((float*)out)[idx] = acc;
}

// ---------------------------------------------------------------------------
extern "C" void kernel_launch(void* const* d_in, const int* in_sizes, int n_in,
                              void* d_out, int out_size, void* d_ws, size_t ws_size,
                              hipStream_t stream) {
  const int* batch = (const int*)d_in[0];
  const void* xsc = d_in[1];
  const void* xsp = d_in[2];

  const int N = in_sizes[0];
  const int G = out_size / 9;

  float* ws  = (float*)d_ws;
  float* res = ws + WS_RES;

  // MFMA path needs room for the expanded bf16 tables and res must not
  // overlap them (res end = 25216 + 9G <= 44032  <=>  G <= 2090).
  const bool big = (ws_size >= (size_t)WS_NEED_BYTES) && (G <= 2090);

  hipMemsetAsync(res, 0, (size_t)G*9*sizeof(float), stream);
  hipMemsetAsync(ws + WS_MOK, 0, sizeof(int), stream);
  detect_kernel<<<1, 64, 0, stream>>>((const u32*)xsp, (int*)(ws + WS_FLAG));
  setup_kernel<<<9, 128, 0, stream>>>(ws);
  convert_weights<<<big ? 16 : 11, 256, 0, stream>>>(d_in[9], d_in[11],
                                          d_in[3], d_in[4], d_in[5],
                                          d_in[6], d_in[7], d_in[8],
                                          d_in[10], d_in[12],
                                          d_in[13], d_in[14], d_in[15],
                                          ws);
  if (big){
    probe_kernel<<<1, 64, 0, stream>>>(ws);
    mfma_kernel<<<(N + 63)/64, 256, 0, stream>>>(batch, xsc, xsp, ws, res, N);
  }

  int nb = (N + TILE - 1) / TILE;
  main_kernel<<<nb, 256, 0, stream>>>(batch, xsc, xsp, ws, res, N);

  finish_kernel<<<(G*9 + 255)/256, 256, 0, stream>>>(res, ws, d_out, G);
}

// Round 2
// 1159.647 us; speedup vs baseline: 1.0211x; 1.0018x over previous
//
#include <hip/hip_runtime.h>
#include <hip/hip_bf16.h>
#include <math.h>

typedef unsigned short u16;
typedef unsigned int   u32;
typedef __attribute__((ext_vector_type(8))) short short8v;
typedef __attribute__((ext_vector_type(4))) float f32x4;

#define TILE 16

// ---------------------------------------------------------------------------
// ws layout (float offsets) — total footprint unchanged from the proven
// 172,864-byte layout (no dependence on ws_size beyond what round 0 used):
//  [0..357)    : the 9 real-basis w3j tensors
//  [368]       : dtype flag (int; 1 = inputs bf16, 0 = f32)
//  [369]       : mfma-layout probe OK flag (int)
//  [384..25168): f32 weight copies (fallback path)  -- OVERLAID by bf16
//                tables when (isbf && mok): tables end at float 12672.
//  [24960..)   : bg1 (64)   [25024..): bg2 (144)  [25168..): C9 (9)
//                (BG1/BG2/C9 are beyond the overlay -> safe for both paths)
//  [25216..)   : res accumulator (G*9 f32)
// ---------------------------------------------------------------------------
#define WS_FLAG  368
#define WS_MOK   369
#define WS_WG1   384
#define WS_WG2   8576
#define WS_WU0   17792
#define WS_WU1   19840
#define WS_WU2   20864
#define WS_WV0   21376
#define WS_WV1   23424
#define WS_WV2   24448
#define WS_BG1   24960
#define WS_BG2   25024
#define WS_C9    25168
#define WS_RES   25216

// u16-element offsets for the compact bf16 tables (overlay, gated on mok):
#define WT_BG1T 768      //  64 x 128 : Bg1T[n][k] = Wg1[k][n]
#define WT_BG2T 8960     // 144 x  64 : Bg2T[n][k] = Wg2[k][n]
#define WT_B0T  18176    //  32 x 128 : rows [U(v=0..15) | V] , k=u
#define WT_B1T  22272    //  32 x  64 : rows [U | V], k=u  (l=1, compact)
#define WT_B2T  24320    //  32 x  32 : rows [U | V], k=u  (l=2, compact)
// table end: 25344 u16 = float 12672  (< WS_BG1=24960, safe)

__device__ __forceinline__ float b2f(u16 u){
  return __uint_as_float(((u32)u) << 16);
}
__device__ __forceinline__ u16 f2b(float f){
  u32 x = __float_as_uint(f);
  return (u16)((x + 0x7fffu + ((x >> 16) & 1u)) >> 16);
}
__device__ __forceinline__ float ldconv(const void* p, int i, int isbf){
  return isbf ? b2f(((const u16*)p)[i]) : ((const float*)p)[i];
}

// ---------------------------------------------------------------------------
// dtype detection
// ---------------------------------------------------------------------------
__global__ void detect_kernel(const u32* __restrict__ words, int* __restrict__ flag){
  int t = threadIdx.x;
  int cnt = 0;
  for (int i = 0; i < 16; i++){
    u32 w = words[t*16 + i];
    u32 e = (w >> 7) & 0xFF;
    cnt += (e >= 117 && e <= 137) ? 1 : 0;
  }
  #pragma unroll
  for (int m = 1; m < 64; m <<= 1) cnt += __shfl_xor(cnt, m, 64);
  if (t == 0) *flag = (cnt > 512) ? 1 : 0;
}

// ---------------------------------------------------------------------------
// Wigner 3j setup
// ---------------------------------------------------------------------------
__device__ double factd(int n){ double r=1.0; for(int i=2;i<=n;++i) r*=(double)i; return r; }

__device__ double su2_cg(int j1,int m1,int j2,int m2,int j3,int m3){
  if (m1+m2 != m3) return 0.0;
  int vmin = max(max(-j1+j2+m3, -j1+m1), 0);
  int vmax = min(min(j2+j3+m1, j3-j1+j2), j3+m3);
  double C = sqrt((2.0*j3+1.0)
      * factd(j3+j1-j2)*factd(j3-j1+j2)*factd(j1+j2-j3)*factd(j3+m3)*factd(j3-m3)
      / (factd(j1+j2+j3+1)*factd(j1-m1)*factd(j1+m1)*factd(j2-m2)*factd(j2+m2)));
  double S = 0.0;
  for (int v=vmin; v<=vmax; ++v){
    double t = factd(j2+j3+m1-v)*factd(j1-m1+v)
             / (factd(v)*factd(j3-j1+j2-v)*factd(j3+m3-v)*factd(v+j1-j2-m3));
    S += ((v+j2+m2)&1) ? -t : t;
  }
  return C*S;
}

__device__ void qmat_lds(int l, double* qre, double* qim){
  int d = 2*l+1;
  for (int i=0;i<d*d;i++){ qre[i]=0.0; qim[i]=0.0; }
  double s = 1.0/sqrt(2.0);
  for (int m=-l; m<0; ++m){
    qre[(l+m)*d + (l-m)] = s;
    qim[(l+m)*d + (l+m)] = -s;
  }
  qre[l*d + l] = 1.0;
  for (int m=1; m<=l; ++m){
    double sgn = (m&1) ? -1.0 : 1.0;
    qre[(l+m)*d + (l+m)] = sgn*s;
    qim[(l+m)*d + (l-m)] = sgn*s;
  }
  double fr, fi;
  switch (l & 3){ case 0: fr=1; fi=0; break; case 1: fr=0; fi=-1; break;
                  case 2: fr=-1; fi=0; break; default: fr=0; fi=1; }
  for (int i=0;i<d*d;i++){
    double a=qre[i], b=qim[i];
    qre[i]=a*fr-b*fi; qim[i]=a*fi+b*fr;
  }
}

__global__ void setup_kernel(float* __restrict__ ws){
  __shared__ double q1r[25], q1i[25], q2r[25], q2i[25], q3r[25], q3i[25];
  __shared__ double red[128];
  const int L1[9]={0,0,1,1,1,2,2,2,2};
  const int L2[9]={0,2,1,1,1,0,2,2,2};
  const int L3[9]={0,2,0,1,2,2,0,1,2};
  const int OFF[9]={0,1,26,35,62,107,132,157,232};
  const int b = blockIdx.x;
  const int l1=L1[b], l2=L2[b], l3=L3[b];
  const int d1=2*l1+1, d2=2*l2+1, d3=2*l3+1;
  const int tot = d1*d2*d3;
  const int t = threadIdx.x;

  if (t==0) qmat_lds(l1, q1r, q1i);
  if (t==1) qmat_lds(l2, q2r, q2i);
  if (t==2) qmat_lds(l3, q3r, q3i);
  __syncthreads();

  double ar = 0.0;
  if (t < tot){
    const int j = t/(d2*d3), rem = t - j*(d2*d3), l = rem/d3, m = rem - l*d3;
    for (int i=0;i<d1;i++){
      double a1r=q1r[i*d1+j], a1i=q1i[i*d1+j];
      for (int k=0;k<d2;k++){
        double a2r=q2r[k*d2+l], a2i=q2i[k*d2+l];
        double t12r = a1r*a2r - a1i*a2i;
        double t12i = a1r*a2i + a1i*a2r;
        for (int n=0;n<d3;n++){
          double c = su2_cg(l1, i-l1, l2, k-l2, l3, n-l3);
          if (c==0.0) continue;
          double a3r = q3r[n*d3+m], a3i = -q3i[n*d3+m]; // conj
          ar += c*(t12r*a3r - t12i*a3i);
        }
      }
    }
  }
  red[t] = ar*ar;
  __syncthreads();
  for (int s=64; s>0; s>>=1){
    if (t < s) red[t] += red[t+s];
    __syncthreads();
  }
  double nrm = sqrt(red[0]);
  if (t < tot) ws[OFF[b] + t] = (float)(ar/nrm);
}

// ---------------------------------------------------------------------------
// Weight canonicalization (f32 copies for the fallback path)
// ---------------------------------------------------------------------------
__global__ void convert_weights(
    const void* Wg1, const void* Wg2,
    const void* WU0, const void* WU1, const void* WU2,
    const void* WV0, const void* WV1, const void* WV2,
    const void* bg1, const void* bg2,
    const void* Wp0, const void* Wp1, const void* Wp2,
    float* __restrict__ ws)
{
  const int isbf = ((const int*)ws)[WS_FLAG];
  const int b = blockIdx.x, t = threadIdx.x;
  if (b < 10){
    const void* src[10] = {Wg1,Wg2,WU0,WU1,WU2,WV0,WV1,WV2,bg1,bg2};
    const int   sz[10]  = {8192,9216,2048,1024,512,2048,1024,512,64,144};
    const int   off[10] = {WS_WG1,WS_WG2,WS_WU0,WS_WU1,WS_WU2,WS_WV0,WS_WV1,WS_WV2,WS_BG1,WS_BG2};
    const void* s = src[b]; float* d = ws + off[b]; int n = sz[b];
    for (int i = t; i < n; i += 256) d[i] = ldconv(s, i, isbf);
  } else if (b == 10 && t == 0){
    float* C9 = ws + WS_C9;
    const int l3k[9]  = {0,2,0,1,2,2,0,1,2};
    const int idxk[9] = {0,0,1,0,1,2,2,1,3};
    for (int k=0;k<9;k++){
      int l3 = l3k[k];
      const void* wp = (l3==0) ? Wp0 : (l3==1) ? Wp1 : Wp2;
      float wpv = ldconv(wp, idxk[k], isbf);
      float len = (l3==0) ? 3.f : (l3==1) ? 2.f : 4.f;
      C9[k] = sqrtf((2.f*l3 + 1.f)/16.f) * wpv * rsqrtf(len);
    }
  }
}

// ---------------------------------------------------------------------------
// MFMA lane-layout probe: asymmetric integer patterns, transpose-detecting.
// Sets ws[WS_MOK]=1 only on exact match.
// ---------------------------------------------------------------------------
__global__ void probe_kernel(float* __restrict__ ws){
  __shared__ u16 A[512];   // [16][32] row-major
  __shared__ u16 B[512];   // [32][16] row-major
  int t = threadIdx.x;
  for (int i=t;i<512;i+=64){
    int m = i >> 5, k = i & 31;
    A[i] = f2b((float)(((3*m + k) % 7) - 3));
    int kk = i >> 4, n = i & 15;
    B[i] = f2b((float)(((2*kk + 5*n) % 9) - 4));
  }
  __syncthreads();
  int v = t & 15, g4 = t >> 4;
  short8v a, b;
  #pragma unroll
  for (int j=0;j<8;j++){
    a[j] = (short)A[v*32 + 8*g4 + j];
    b[j] = (short)B[(8*g4 + j)*16 + v];
  }
  f32x4 c = {0.f,0.f,0.f,0.f};
  c = __builtin_amdgcn_mfma_f32_16x16x32_bf16(a, b, c, 0, 0, 0);
  int ok = 1;
  #pragma unroll
  for (int r=0;r<4;r++){
    int row = 4*g4 + r;
    float ref = 0.f;
    for (int k=0;k<32;k++) ref += b2f(A[row*32+k]) * b2f(B[k*16+v]);
    if (fabsf(c[r] - ref) > 0.25f) ok = 0;
  }
  #pragma unroll
  for (int m=1;m<64;m<<=1) ok &= __shfl_xor(ok, m, 64);
  if (t == 0) ((int*)ws)[WS_MOK] = ok;
}

// ---------------------------------------------------------------------------
// Compact bf16 table builder — OVERLAYS the f32 weight-copy region.
// Device-gated: only runs when the MFMA path is live (then the fallback
// early-exits and never reads the overlaid f32 copies). Inputs are raw bf16
// when isbf, so the copies are bit-exact.
// ---------------------------------------------------------------------------
__global__ void convert_tables(
    const void* Wg1, const void* Wg2,
    const void* WU0, const void* WU1, const void* WU2,
    const void* WV0, const void* WV1, const void* WV2,
    float* __restrict__ ws)
{
  const int isbf = ((const int*)ws)[WS_FLAG];
  const int mok  = ((const int*)ws)[WS_MOK];
  if (!(isbf && mok)) return;
  u16* wh = (u16*)ws;
  const int b = blockIdx.x, t = threadIdx.x;
  if (b == 0){          // Bg1T[n=64][k=128] = Wg1[k][n]
    for (int i=t;i<8192;i+=256){
      int n = i >> 7, k = i & 127;
      wh[WT_BG1T + i] = ((const u16*)Wg1)[k*64 + n];
    }
  } else if (b == 1){   // Bg2T[n=144][k=64] = Wg2[k][n]
    for (int i=t;i<9216;i+=256){
      int n = i >> 6, k = i & 63;
      wh[WT_BG2T + i] = ((const u16*)Wg2)[k*144 + n];
    }
  } else if (b == 2){   // B0T[n=32][k=128] = [WU0|WV0]^T
    for (int i=t;i<4096;i+=256){
      int n = i >> 7, k = i & 127;
      wh[WT_B0T + i] = (n < 16) ? ((const u16*)WU0)[k*16 + n]
                                : ((const u16*)WV0)[k*16 + (n-16)];
    }
  } else if (b == 3){   // B1T[n=32][k=64] = [WU1|WV1]^T (compact)
    for (int i=t;i<2048;i+=256){
      int n = i >> 6, u = i & 63;
      wh[WT_B1T + i] = (n < 16) ? ((const u16*)WU1)[u*16 + n]
                                : ((const u16*)WV1)[u*16 + (n-16)];
    }
  } else if (b == 4){   // B2T[n=32][k=32] = [WU2|WV2]^T (compact)
    for (int i=t;i<1024;i+=256){
      int n = i >> 5, u = i & 31;
      wh[WT_B2T + i] = (n < 16) ? ((const u16*)WU2)[u*16 + n]
                                : ((const u16*)WV2)[u*16 + (n-16)];
    }
  }
}

// ---------------------------------------------------------------------------
// MFMA main kernel (bf16 inputs only). One wave = 16 atoms; 4 waves/block.
// G1/G2/l0 via contiguous fragments; l1/l2 via compact-B + strided-A gathers
// (8 scalar u16 loads per fragment, imm-offset folded, L1-resident).
// ---------------------------------------------------------------------------
__global__ __launch_bounds__(256,2) void mfma_kernel(
    const int* __restrict__ batch,
    const void* __restrict__ xscv,
    const void* __restrict__ xspv,
    const float* __restrict__ ws,
    float* __restrict__ res,
    int N)
{
  const int isbf = ((const int*)ws)[WS_FLAG];
  const int mok  = ((const int*)ws)[WS_MOK];
  if (!(isbf && mok)) return;

  __shared__ __align__(16) u16 H1hi[4][16][72];
  __shared__ __align__(16) u16 H1lo[4][16][72];

  const int tid = threadIdx.x;
  const int wave = tid >> 6, lane = tid & 63;
  const int v = lane & 15, g4 = lane >> 4;
  const int tile = blockIdx.x*4 + wave;
  const int n0 = tile * TILE;
  if (n0 >= N) return;

  const u16* xsc = (const u16*)xscv;
  const u16* xsp = (const u16*)xspv;
  const u16* wb  = (const u16*)ws;

  int rowA = n0 + v; if (rowA >= N) rowA = N - 1;

  // ---- G1: H1pre = Xsc(16x128) @ Wg1(128x64) --------------------------------
  f32x4 accg[4];
  #pragma unroll
  for (int nt=0;nt<4;nt++) accg[nt] = (f32x4){0.f,0.f,0.f,0.f};
  {
    const u16* aP = xsc + (size_t)rowA*128 + 8*g4;
    const u16* bP = wb + WT_BG1T + v*128 + 8*g4;
    #pragma unroll
    for (int kt=0;kt<4;kt++){
      short8v a = *(const short8v*)(aP + kt*32);
      #pragma unroll
      for (int nt=0;nt<4;nt++){
        short8v b = *(const short8v*)(bP + nt*2048 + kt*32);
        accg[nt] = __builtin_amdgcn_mfma_f32_16x16x32_bf16(a, b, accg[nt], 0, 0, 0);
      }
    }
  }
  // bias + silu + hi/lo bf16 split -> LDS transpose (D: row=atom, col=feat)
  #pragma unroll
  for (int nt=0;nt<4;nt++){
    float bb = ws[WS_BG1 + nt*16 + v];
    #pragma unroll
    for (int r=0;r<4;r++){
      float hs = accg[nt][r] + bb;
      float h  = hs / (1.f + __expf(-hs));
      u16 hi = f2b(h);
      float lo = h - b2f(hi);
      int atom = 4*g4 + r;
      H1hi[wave][atom][nt*16 + v] = hi;
      H1lo[wave][atom][nt*16 + v] = f2b(lo);
    }
  }
  // same-wave ds_write -> ds_read: wave-synchronous; compiler orders via lgkmcnt

  // ---- G2: W = H1(16x64) @ Wg2(64x144), split-bf16 for f32-grade precision --
  f32x4 accw[9];
  #pragma unroll
  for (int nt=0;nt<9;nt++) accw[nt] = (f32x4){0.f,0.f,0.f,0.f};
  {
    const u16* hH = &H1hi[wave][v][8*g4];
    const u16* hL = &H1lo[wave][v][8*g4];
    const u16* bP = wb + WT_BG2T + v*64 + 8*g4;
    #pragma unroll
    for (int kt=0;kt<2;kt++){
      short8v ah = *(const short8v*)(hH + kt*32);
      short8v al = *(const short8v*)(hL + kt*32);
      #pragma unroll
      for (int nt=0;nt<9;nt++){
        short8v b = *(const short8v*)(bP + nt*1024 + kt*32);
        accw[nt] = __builtin_amdgcn_mfma_f32_16x16x32_bf16(ah, b, accw[nt], 0, 0, 0);
        accw[nt] = __builtin_amdgcn_mfma_f32_16x16x32_bf16(al, b, accw[nt], 0, 0, 0);
      }
    }
  }
  float wkv[9][4];
  #pragma unroll
  for (int nt=0;nt<9;nt++){
    float bb = ws[WS_BG2 + nt*16 + v];
    float c9 = ws[WS_C9 + nt];
    #pragma unroll
    for (int r=0;r<4;r++) wkv[nt][r] = (accw[nt][r] + bb) * c9;
  }

  // ---- l=0 linear: [hU0|hV0] = Xsp[:, :128] @ B0T^T -------------------------
  const u16* spRow = xsp + (size_t)rowA*480;

  f32x4 acc0[2];
  #pragma unroll
  for (int nt=0;nt<2;nt++) acc0[nt] = (f32x4){0.f,0.f,0.f,0.f};
  {
    const u16* aP = spRow + 8*g4;
    const u16* bP = wb + WT_B0T + v*128 + 8*g4;
    #pragma unroll
    for (int kt=0;kt<4;kt++){
      short8v a = *(const short8v*)(aP + kt*32);
      #pragma unroll
      for (int nt=0;nt<2;nt++){
        short8v b = *(const short8v*)(bP + nt*2048 + kt*32);
        acc0[nt] = __builtin_amdgcn_mfma_f32_16x16x32_bf16(a, b, acc0[nt], 0, 0, 0);
      }
    }
  }

  // ---- l=1: compact B (K=64) x 3 components, strided-A gathers --------------
  f32x4 accA[6];
  #pragma unroll
  for (int nt=0;nt<6;nt++) accA[nt] = (f32x4){0.f,0.f,0.f,0.f};
  {
    const u16* bU = wb + WT_B1T + v*64 + 8*g4;
    const u16* bV = wb + WT_B1T + (16+v)*64 + 8*g4;
    short8v bu0 = *(const short8v*)(bU);
    short8v bu1 = *(const short8v*)(bU + 32);
    short8v bv0 = *(const short8v*)(bV);
    short8v bv1 = *(const short8v*)(bV + 32);
    #pragma unroll
    for (int i=0;i<3;i++){
      #pragma unroll
      for (int kt=0;kt<2;kt++){
        const u16* ap = spRow + 128 + i + 3*(32*kt + 8*g4);
        short8v a;
        #pragma unroll
        for (int j=0;j<8;j++) a[j] = (short)ap[3*j];
        short8v bu = kt ? bu1 : bu0;
        short8v bv = kt ? bv1 : bv0;
        accA[i]   = __builtin_amdgcn_mfma_f32_16x16x32_bf16(a, bu, accA[i],   0, 0, 0);
        accA[3+i] = __builtin_amdgcn_mfma_f32_16x16x32_bf16(a, bv, accA[3+i], 0, 0, 0);
      }
    }
  }

  // ---- l=2: compact B (K=32) x 5 components, strided-A gathers --------------
  f32x4 accB[10];
  #pragma unroll
  for (int nt=0;nt<10;nt++) accB[nt] = (f32x4){0.f,0.f,0.f,0.f};
  {
    short8v b2u = *(const short8v*)(wb + WT_B2T + v*32 + 8*g4);
    short8v b2v = *(const short8v*)(wb + WT_B2T + (16+v)*32 + 8*g4);
    #pragma unroll
    for (int i=0;i<5;i++){
      const u16* ap = spRow + 320 + i + 5*(8*g4);
      short8v a;
      #pragma unroll
      for (int j=0;j<8;j++) a[j] = (short)ap[5*j];
      accB[i]   = __builtin_amdgcn_mfma_f32_16x16x32_bf16(a, b2u, accB[i],   0, 0, 0);
      accB[5+i] = __builtin_amdgcn_mfma_f32_16x16x32_bf16(a, b2v, accB[5+i], 0, 0, 0);
    }
  }

  // ---- phase 4: tensor products, u-reduction, merged segment atomics --------
  int bidr[4];
  #pragma unroll
  for (int r=0;r<4;r++){
    int n = n0 + 4*g4 + r;
    bidr[r] = (n < N) ? batch[n] : -1;
  }

  const float r128 = 0.088388347648318447f;
  const float r64  = 0.125f;
  const float r32  = 0.17677669529663689f;
  const float* J = ws;
  float pend[9];
  int pg = -1;

  #pragma unroll
  for (int r=0;r<4;r++){
    float hu0 = acc0[0][r]*r128, hv0 = acc0[1][r]*r128;
    float hu1[3], hv1[3], hu2[5], hv2[5];
    #pragma unroll
    for (int i=0;i<3;i++){ hu1[i] = accA[i][r]*r64; hv1[i] = accA[3+i][r]*r64; }
    #pragma unroll
    for (int i=0;i<5;i++){ hu2[i] = accB[i][r]*r32; hv2[i] = accB[5+i][r]*r32; }

    float t9[9] = {0,0,0,0,0,0,0,0,0};
    t9[0] += wkv[0][r]*J[0]*hu0*hv0;
    {
      float cw = wkv[1][r]*hu0;
      #pragma unroll
      for (int m=0;m<5;m++){
        float s=0.f;
        #pragma unroll
        for (int j=0;j<5;j++) s += J[1 + j*5 + m]*hv2[j];
        t9[4+m] += cw*s;
      }
    }
    {
      float s=0.f;
      #pragma unroll
      for (int i=0;i<3;i++)
        #pragma unroll
        for (int j=0;j<3;j++) s += J[26 + i*3 + j]*hu1[i]*hv1[j];
      t9[0] += wkv[2][r]*s;
    }
    {
      float sm[3]={0,0,0};
      #pragma unroll
      for (int i=0;i<3;i++)
        #pragma unroll
        for (int j=0;j<3;j++){
          float p = hu1[i]*hv1[j];
          #pragma unroll
          for (int m=0;m<3;m++) sm[m] += J[35 + (i*3+j)*3 + m]*p;
        }
      #pragma unroll
      for (int m=0;m<3;m++) t9[1+m] += wkv[3][r]*sm[m];
    }
    {
      float sm[5]={0,0,0,0,0};
      #pragma unroll
      for (int i=0;i<3;i++)
        #pragma unroll
        for (int j=0;j<3;j++){
          float p = hu1[i]*hv1[j];
          #pragma unroll
          for (int m=0;m<5;m++) sm[m] += J[62 + (i*3+j)*5 + m]*p;
        }
      #pragma unroll
      for (int m=0;m<5;m++) t9[4+m] += wkv[4][r]*sm[m];
    }
    {
      float cw = wkv[5][r]*hv0;
      #pragma unroll
      for (int m=0;m<5;m++){
        float s=0.f;
        #pragma unroll
        for (int i=0;i<5;i++) s += J[107 + i*5 + m]*hu2[i];
        t9[4+m] += cw*s;
      }
    }
    {
      float s=0.f;
      #pragma unroll
      for (int i=0;i<5;i++)
        #pragma unroll
        for (int j=0;j<5;j++) s += J[132 + i*5 + j]*hu2[i]*hv2[j];
      t9[0] += wkv[6][r]*s;
    }
    {
      float sm[3]={0,0,0};
      #pragma unroll
      for (int i=0;i<5;i++)
        #pragma unroll
        for (int j=0;j<5;j++){
          float p = hu2[i]*hv2[j];
          #pragma unroll
          for (int m=0;m<3;m++) sm[m] += J[157 + (i*5+j)*3 + m]*p;
        }
      #pragma unroll
      for (int m=0;m<3;m++) t9[1+m] += wkv[7][r]*sm[m];
    }
    {
      float sm[5]={0,0,0,0,0};
      #pragma unroll
      for (int i=0;i<5;i++)
        #pragma unroll
        for (int j=0;j<5;j++){
          float p = hu2[i]*hv2[j];
          #pragma unroll
          for (int m=0;m<5;m++) sm[m] += J[232 + (i*5+j)*5 + m]*p;
        }
      #pragma unroll
      for (int m=0;m<5;m++) t9[4+m] += wkv[8][r]*sm[m];
    }

    #pragma unroll
    for (int mask=1; mask<16; mask<<=1){
      #pragma unroll
      for (int s=0;s<9;s++) t9[s] += __shfl_xor(t9[s], mask, 64);
    }
    if (v == 0){
      int n = n0 + 4*g4 + r;
      if (n < N){
        int g = bidr[r];
        if (g == pg){
          #pragma unroll
          for (int s=0;s<9;s++) pend[s] += t9[s];
        } else {
          if (pg >= 0){
            float* rp = res + (size_t)pg*9;
            #pragma unroll
            for (int s=0;s<9;s++) atomicAdd(&rp[s], pend[s]);
          }
          pg = g;
          #pragma unroll
          for (int s=0;s<9;s++) pend[s] = t9[s];
        }
      }
    }
  }
  if (v == 0 && pg >= 0){
    float* rp = res + (size_t)pg*9;
    #pragma unroll
    for (int s=0;s<9;s++) atomicAdd(&rp[s], pend[s]);
  }
}

// ---------------------------------------------------------------------------
// Fallback scalar kernel (f32 inputs, or MFMA probe failure).
// ---------------------------------------------------------------------------
__device__ __forceinline__ void load8_bf16(const u16* p, float* dst){
  uint4 vv = *reinterpret_cast<const uint4*>(p);
  u32 w[4] = {vv.x, vv.y, vv.z, vv.w};
  #pragma unroll
  for (int q=0;q<4;q++){
    dst[2*q]   = __uint_as_float((w[q] & 0xffffu) << 16);
    dst[2*q+1] = __uint_as_float(w[q] & 0xffff0000u);
  }
}
__device__ __forceinline__ void load8_f32(const float* p, float* dst){
  float4 v0 = *reinterpret_cast<const float4*>(p);
  float4 v1 = *reinterpret_cast<const float4*>(p+4);
  dst[0]=v0.x; dst[1]=v0.y; dst[2]=v0.z; dst[3]=v0.w;
  dst[4]=v1.x; dst[5]=v1.y; dst[6]=v1.z; dst[7]=v1.w;
}

__global__ __launch_bounds__(256) void main_kernel(
    const int* __restrict__ batch,
    const void* __restrict__ xscv,
    const void* __restrict__ xspv,
    const float* __restrict__ ws,
    float* __restrict__ res,
    int N)
{
  {
    const int fb = ((const int*)ws)[WS_FLAG];
    const int mk = ((const int*)ws)[WS_MOK];
    if (fb && mk) return;   // MFMA path handled it
  }
  __shared__ float s_xsph[TILE][481];
  __shared__ float s_w[TILE][144];
  __shared__ float s_uni[4624];
  __shared__ float s_w3j[357];
  __shared__ float s_bg1[64];
  __shared__ float s_bg2[144];
  __shared__ float s_C[9];
  __shared__ int   s_batch[TILE];

  float (*s_xs)[128] = reinterpret_cast<float(*)[128]>(s_uni);
  float (*s_h1)[64]  = reinterpret_cast<float(*)[64]>(s_uni + 2048);
  float (*s_hU)[144] = reinterpret_cast<float(*)[144]>(s_uni);
  float (*s_hV)[144] = reinterpret_cast<float(*)[144]>(s_uni + 2304);

  const int tid  = threadIdx.x;
  const int wave = tid >> 6;
  const int lane = tid & 63;
  const int n0   = blockIdx.x * TILE;
  const int isbf = ((const int*)ws)[WS_FLAG];

  const float* wsWg1 = ws + WS_WG1;
  const float* wsWg2 = ws + WS_WG2;
  const float* wsWU0 = ws + WS_WU0;
  const float* wsWU1 = ws + WS_WU1;
  const float* wsWU2 = ws + WS_WU2;
  const float* wsWV0 = ws + WS_WV0;
  const float* wsWV1 = ws + WS_WV1;
  const float* wsWV2 = ws + WS_WV2;

  if (tid < TILE){ int n = n0 + tid; s_batch[tid] = (n < N) ? batch[n] : -1; }
  if (tid < 64)  s_bg1[tid] = ws[WS_BG1 + tid];
  if (tid < 144) s_bg2[tid] = ws[WS_BG2 + tid];
  if (tid < 9)   s_C[tid]   = ws[WS_C9 + tid];
  for (int i = tid; i < 357; i += 256) s_w3j[i] = ws[i];
  {
    int base = tid*8, row = base >> 7, col = base & 127;
    int n = n0 + row;
    if (n < N){
      if (isbf) load8_bf16((const u16*)xscv + (size_t)n*128 + col, &s_xs[row][col]);
      else      load8_f32 ((const float*)xscv + (size_t)n*128 + col, &s_xs[row][col]);
    } else { for (int q=0;q<8;q++) s_xs[row][col+q] = 0.f; }
  }
  {
    for (int it = tid; it < 960; it += 256){
      int base = it*8, row = base/480, col = base - row*480;
      int n = n0 + row;
      if (n < N){
        if (isbf) load8_bf16((const u16*)xspv + (size_t)n*480 + col, &s_xsph[row][col]);
        else      load8_f32 ((const float*)xspv + (size_t)n*480 + col, &s_xsph[row][col]);
      } else { for (int q=0;q<8;q++) s_xsph[row][col+q] = 0.f; }
    }
  }
  __syncthreads();

  {
    const int a0 = wave*4;
    float acc0=s_bg1[lane], acc1=acc0, acc2=acc0, acc3=acc0;
    for (int c=0;c<128;c++){
      float wv = wsWg1[c*64 + lane];
      acc0 += s_xs[a0+0][c]*wv;
      acc1 += s_xs[a0+1][c]*wv;
      acc2 += s_xs[a0+2][c]*wv;
      acc3 += s_xs[a0+3][c]*wv;
    }
    s_h1[a0+0][lane] = acc0/(1.f+__expf(-acc0));
    s_h1[a0+1][lane] = acc1/(1.f+__expf(-acc1));
    s_h1[a0+2][lane] = acc2/(1.f+__expf(-acc2));
    s_h1[a0+3][lane] = acc3/(1.f+__expf(-acc3));
  }
  __syncthreads();

  {
    const int a0 = wave*4;
    float acc[4][3];
    #pragma unroll
    for (int t=0;t<4;t++){
      acc[t][0] = s_bg2[lane];
      acc[t][1] = s_bg2[64+lane];
      acc[t][2] = (lane<16) ? s_bg2[128+lane] : 0.f;
    }
    for (int c=0;c<64;c++){
      float w0 = wsWg2[c*144 + lane];
      float w1 = wsWg2[c*144 + 64 + lane];
      float w2 = (lane<16) ? wsWg2[c*144 + 128 + lane] : 0.f;
      #pragma unroll
      for (int t=0;t<4;t++){
        float h = s_h1[a0+t][c];
        acc[t][0] += h*w0; acc[t][1] += h*w1; acc[t][2] += h*w2;
      }
    }
    #pragma unroll
    for (int t=0;t<4;t++){
      s_w[a0+t][lane]    = acc[t][0];
      s_w[a0+t][64+lane] = acc[t][1];
      if (lane < 16) s_w[a0+t][128+lane] = acc[t][2];
    }
  }
  __syncthreads();

  {
    const int a = tid >> 4, v = tid & 15;
    const float r128 = 0.088388347648318447f;
    const float r64  = 0.125f;
    const float r32  = 0.17677669529663689f;
    {
      float aU=0.f, aV=0.f;
      for (int u=0;u<128;u++){
        float x = s_xsph[a][u];
        aU += x*wsWU0[u*16+v];
        aV += x*wsWV0[u*16+v];
      }
      s_hU[a][v] = aU*r128; s_hV[a][v] = aV*r128;
    }
    {
      float aU[3]={0,0,0}, aV[3]={0,0,0};
      for (int u=0;u<64;u++){
        float wu = wsWU1[u*16+v], wv = wsWV1[u*16+v];
        #pragma unroll
        for (int i=0;i<3;i++){
          float x = s_xsph[a][128 + u*3 + i];
          aU[i] += x*wu; aV[i] += x*wv;
        }
      }
      #pragma unroll
      for (int i=0;i<3;i++){ s_hU[a][16+v*3+i]=aU[i]*r64; s_hV[a][16+v*3+i]=aV[i]*r64; }
    }
    {
      float aU[5]={0,0,0,0,0}, aV[5]={0,0,0,0,0};
      for (int u=0;u<32;u++){
        float wu = wsWU2[u*16+v], wv = wsWV2[u*16+v];
        #pragma unroll
        for (int i=0;i<5;i++){
          float x = s_xsph[a][320 + u*5 + i];
          aU[i] += x*wu; aV[i] += x*wv;
        }
      }
      #pragma unroll
      for (int i=0;i<5;i++){ s_hU[a][64+v*5+i]=aU[i]*r32; s_hV[a][64+v*5+i]=aV[i]*r32; }
    }
  }
  __syncthreads();

  {
    const int a = tid >> 4, u = tid & 15;
    float hu0 = s_hU[a][u], hv0 = s_hV[a][u];
    float hu1[3], hv1[3], hu2[5], hv2[5];
    #pragma unroll
    for (int i=0;i<3;i++){ hu1[i]=s_hU[a][16+u*3+i]; hv1[i]=s_hV[a][16+u*3+i]; }
    #pragma unroll
    for (int i=0;i<5;i++){ hu2[i]=s_hU[a][64+u*5+i]; hv2[i]=s_hV[a][64+u*5+i]; }
    float wk[9];
    #pragma unroll
    for (int k=0;k<9;k++) wk[k] = s_w[a][k*16+u];

    const float* J = s_w3j;
    float t9[9] = {0,0,0,0,0,0,0,0,0};

    t9[0] += s_C[0]*wk[0]*J[0]*hu0*hv0;
    {
      float cw = s_C[1]*wk[1]*hu0;
      #pragma unroll
      for (int m=0;m<5;m++){
        float s=0.f;
        #pragma unroll
        for (int j=0;j<5;j++) s += J[1 + j*5 + m]*hv2[j];
        t9[4+m] += cw*s;
      }
    }
    {
      float s=0.f;
      #pragma unroll
      for (int i=0;i<3;i++)
        #pragma unroll
        for (int j=0;j<3;j++) s += J[26 + i*3 + j]*hu1[i]*hv1[j];
      t9[0] += s_C[2]*wk[2]*s;
    }
    {
      float sm[3]={0,0,0};
      #pragma unroll
      for (int i=0;i<3;i++)
        #pragma unroll
        for (int j=0;j<3;j++){
          float p = hu1[i]*hv1[j];
          #pragma unroll
          for (int m=0;m<3;m++) sm[m] += J[35 + (i*3+j)*3 + m]*p;
        }
      float c = s_C[3]*wk[3];
      #pragma unroll
      for (int m=0;m<3;m++) t9[1+m] += c*sm[m];
    }
    {
      float sm[5]={0,0,0,0,0};
      #pragma unroll
      for (int i=0;i<3;i++)
        #pragma unroll
        for (int j=0;j<3;j++){
          float p = hu1[i]*hv1[j];
          #pragma unroll
          for (int m=0;m<5;m++) sm[m] += J[62 + (i*3+j)*5 + m]*p;
        }
      float c = s_C[4]*wk[4];
      #pragma unroll
      for (int m=0;m<5;m++) t9[4+m] += c*sm[m];
    }
    {
      float cw = s_C[5]*wk[5]*hv0;
      #pragma unroll
      for (int m=0;m<5;m++){
        float s=0.f;
        #pragma unroll
        for (int i=0;i<5;i++) s += J[107 + i*5 + m]*hu2[i];
        t9[4+m] += cw*s;
      }
    }
    {
      float s=0.f;
      #pragma unroll
      for (int i=0;i<5;i++)
        #pragma unroll
        for (int j=0;j<5;j++) s += J[132 + i*5 + j]*hu2[i]*hv2[j];
      t9[0] += s_C[6]*wk[6]*s;
    }
    {
      float sm[3]={0,0,0};
      #pragma unroll
      for (int i=0;i<5;i++)
        #pragma unroll
        for (int j=0;j<5;j++){
          float p = hu2[i]*hv2[j];
          #pragma unroll
          for (int m=0;m<3;m++) sm[m] += J[157 + (i*5+j)*3 + m]*p;
        }
      float c = s_C[7]*wk[7];
      #pragma unroll
      for (int m=0;m<3;m++) t9[1+m] += c*sm[m];
    }
    {
      float sm[5]={0,0,0,0,0};
      #pragma unroll
      for (int i=0;i<5;i++)
        #pragma unroll
        for (int j=0;j<5;j++){
          float p = hu2[i]*hv2[j];
          #pragma unroll
          for (int m=0;m<5;m++) sm[m] += J[232 + (i*5+j)*5 + m]*p;
        }
      float c = s_C[8]*wk[8];
      #pragma unroll
      for (int m=0;m<5;m++) t9[4+m] += c*sm[m];
    }

    #pragma unroll
    for (int mask=1; mask<16; mask<<=1){
      #pragma unroll
      for (int s=0;s<9;s++) t9[s] += __shfl_xor(t9[s], mask, 64);
    }
    if (u == 0 && (n0 + a) < N){
      int g = s_batch[a];
      float* r = res + (size_t)g*9;
      #pragma unroll
      for (int s=0;s<9;s++) atomicAdd(&r[s], t9[s]);
    }
  }
}

// ---------------------------------------------------------------------------
// Finish: res_sph (G x 9) -> out (G x 3 x 3) via Q_COB + CART permutation
// ---------------------------------------------------------------------------
__global__ void finish_kernel(const float* __restrict__ res,
                              const float* __restrict__ ws,
                              void* __restrict__ out, int G)
{
  int idx = blockIdx.x*256 + threadIdx.x;
  if (idx >= G*9) return;
  const int isbf = ((const int*)ws)[WS_FLAG];
  int g = idx/9, s = idx - g*9;
  int a = s/3, b = s - a*3;
  const int cart[3] = {2,0,1};
  int ca = cart[a], cb = cart[b];
  const float s3 = 1.7320508075688772f, s5 = 2.2360679774997896f;
  const float* r = res + (size_t)g*9;
  float acc = r[0]*ws[26 + ca*3 + cb];
  #pragma unroll
  for (int m=0;m<3;m++) acc += r[1+m]*s3*ws[35 + (ca*3+cb)*3 + m];
  #pragma unroll
  for (int m=0;m<5;m++) acc += r[4+m]*s5*ws[62 + (ca*3+cb)*5 + m];
  if (isbf) ((__hip_bfloat16*)out)[idx] = __float2bfloat16(acc);
  else      ((float*)out)[idx] = acc;
}

// ---------------------------------------------------------------------------
extern "C" void kernel_launch(void* const* d_in, const int* in_sizes, int n_in,
                              void* d_out, int out_size, void* d_ws, size_t ws_size,
                              hipStream_t stream) {
  const int* batch = (const int*)d_in[0];
  const void* xsc = d_in[1];
  const void* xsp = d_in[2];

  const int N = in_sizes[0];
  const int G = out_size / 9;

  float* ws  = (float*)d_ws;
  float* res = ws + WS_RES;

  hipMemsetAsync(res, 0, (size_t)G*9*sizeof(float), stream);
  hipMemsetAsync(ws + WS_MOK, 0, sizeof(int), stream);
  detect_kernel<<<1, 64, 0, stream>>>((const u32*)xsp, (int*)(ws + WS_FLAG));
  setup_kernel<<<9, 128, 0, stream>>>(ws);
  convert_weights<<<11, 256, 0, stream>>>(d_in[9], d_in[11],
                                          d_in[3], d_in[4], d_in[5],
                                          d_in[6], d_in[7], d_in[8],
                                          d_in[10], d_in[12],
                                          d_in[13], d_in[14], d_in[15],
                                          ws);
  probe_kernel<<<1, 64, 0, stream>>>(ws);
  convert_tables<<<5, 256, 0, stream>>>(d_in[9], d_in[11],
                                        d_in[3], d_in[4], d_in[5],
                                        d_in[6], d_in[7], d_in[8],
                                        ws);
  mfma_kernel<<<(N + 63)/64, 256, 0, stream>>>(batch, xsc, xsp, ws, res, N);

  int nb = (N + TILE - 1) / TILE;
  main_kernel<<<nb, 256, 0, stream>>>(batch, xsc, xsp, ws, res, N);

  finish_kernel<<<(G*9 + 255)/256, 256, 0, stream>>>(res, ws, d_out, G);
}